// Round 4
// baseline (183.410 us; speedup 1.0000x reference)
//
#include <hip/hip_runtime.h>
#include <hip/hip_bf16.h>
#include <stdint.h>
#include <stddef.h>

typedef __bf16 bf16;
typedef __bf16 bf16x4 __attribute__((ext_vector_type(4)));
typedef __bf16 bf16x8 __attribute__((ext_vector_type(8)));
typedef float f32x4 __attribute__((ext_vector_type(4)));

#define BATCH 4096
#define KIH 7808          // Wih K
#define KTOT 7936         // 62 slots * 128 (h0 appended)
#define NG 512            // 4*LH gates
#define LH 128
#define HD 64
#define ED 128
#define SPLITK 4

// workspace layout (byte offsets)
#define OFF_WCAT 0u                 //  8,126,464  bf16 Wcat[512][7936]
#define OFF_GPART 8126464u          // 16,777,216  bf16 gpart[4][4096][512]
#define OFF_XT   24903680u          //  2,097,152  bf16 xtail[4096][256]
#define OFF_AB   27000832u          //     76,800  bf16 ab8[300][128]
#define OFF_MV   27077632u          //    230,400  bf16 mv8[900][128]
#define OFF_ADDR 27308032u          //  1,048,576  u32 addrs[4096][64]
#define OFF_W1F  29405184u          //     16,384  bf16 W1 fragments
#define OFF_W2F  29421568u          //     16,384  bf16 W2 fragments
#define OFF_WAF  29437952u          //      4,096  bf16 Wa fragments
#define OFF_NB   29442048u          //      2,048  f32 nbias[512]
// end: 29,444,096 B

// out layout: probs[B*9] | h1[B*128] | c1[B*128]
#define O_H1 (BATCH * 9)
#define O_C1 (BATCH * 9 + BATCH * LH)

// prep grid partition
#define PREP_BP 2048                 // build_pre: 2 rows/block
#define PREP_CW (PREP_BP + 512)      // convert_w
#define PREP_CE (PREP_CW + 150)      // convert_emb (float4 x 256 x 150 = 153600)
#define PREP_TOT (PREP_CE + 1)       // + MLP fragment pack

// ---------------------------------------------------------------------------
typedef const __attribute__((address_space(1))) uint32_t* gas_ptr;
typedef __attribute__((address_space(3))) uint32_t* las_ptr;

__device__ __forceinline__ void async16(const void* g, void* l) {
    __builtin_amdgcn_global_load_lds((gas_ptr)g, (las_ptr)l, 16, 0, 0);
}

// ---------------------------------------------------------------------------
// Kernel 1: fused prep (verbatim from the verified version).
// ---------------------------------------------------------------------------
__global__ void prep(const int* __restrict__ ab_ids,
                     const int* __restrict__ mv_ids,
                     const float* __restrict__ numerical,
                     const float* __restrict__ h0,
                     const float* __restrict__ numW,
                     const float* __restrict__ numb,
                     const float* __restrict__ Wih,
                     const float* __restrict__ Whh,
                     const float* __restrict__ ab_emb,
                     const float* __restrict__ mv_emb,
                     const float* __restrict__ W1,
                     const float* __restrict__ W2,
                     const float* __restrict__ Wa,
                     uint8_t* __restrict__ ws) {
    const int bid = blockIdx.x;
    const int t = threadIdx.x;  // 0..255

    if (bid < PREP_BP) {
        // ---- build_pre: 2 rows per block; half-block (128 thr) per row ----
        bf16* xtail = (bf16*)(ws + OFF_XT);
        uint32_t* addrs = (uint32_t*)(ws + OFF_ADDR);
        const int h = t >> 7;            // row half 0/1
        const int th = t & 127;
        const int b = bid * 2 + h;

        __shared__ int ids[2][60];
        if (th < 60)
            ids[h][th] = (th < 12) ? ab_ids[b * 12 + th]
                                   : mv_ids[b * 48 + (th - 12)];

        const float v = (th < 84) ? numerical[(size_t)b * 84 + th] : 0.f;
        xtail[(size_t)b * 256 + th] = (bf16)v;
        xtail[(size_t)b * 256 + 128 + th] = (bf16)h0[(size_t)b * LH + th];
        __syncthreads();

        if (th < 64) {
            uint32_t off;
            if (th < 12) off = OFF_AB + (uint32_t)ids[h][th] * 256u;
            else if (th < 60) off = OFF_MV + (uint32_t)ids[h][th] * 256u;
            else if (th == 60) off = OFF_XT + (uint32_t)b * 512u;
            else if (th == 61) off = OFF_XT + (uint32_t)b * 512u + 256u;
            else off = OFF_XT;  // unused slots 62,63
            addrs[(size_t)b * 64 + th] = off;
        }
    } else if (bid < PREP_CW) {
        // ---- convert_w: cols [0,7680) direct; slot 60 = Wfold; then Whh ----
        bf16* Wcat = (bf16*)(ws + OFF_WCAT);
        float* nbias = (float*)(ws + OFF_NB);
        const int n = bid - PREP_BP;

        __shared__ float wrow[128];   // Wih[n][7680..7808)
        __shared__ float nbs[128];
        if (t < 128) wrow[t] = Wih[(size_t)n * KIH + 7680 + t];
        else nbs[t - 128] = numb[t - 128];
        __syncthreads();

        const float* src_ih = Wih + (size_t)n * KIH;
        bf16* dst = Wcat + (size_t)n * KTOT;
        for (int k4 = t; k4 < 1920; k4 += 256) {   // 7680/4
            const int k = k4 * 4;
            const float4 v = *(const float4*)(src_ih + k);
            bf16x4 o = {(bf16)v.x, (bf16)v.y, (bf16)v.z, (bf16)v.w};
            *(bf16x4*)(dst + k) = o;
        }
        if (t < 84) {
            // Wfold[n][t] = sum_e Wih[n][7680+e] * numW[e][t]
            float acc = 0.f;
#pragma unroll 4
            for (int e = 0; e < 128; ++e)
                acc += wrow[e] * numW[e * 84 + t];
            dst[7680 + t] = (bf16)acc;
        } else if (t < 128) {
            dst[7680 + t] = (bf16)0.f;     // padding cols (x is zero there too)
        } else {
            const int tt = t - 128;
            dst[KIH + tt] = (bf16)Whh[(size_t)n * LH + tt];
        }
        if (t == 255) {
            float a = 0.f;
#pragma unroll 4
            for (int e = 0; e < 128; ++e) a += wrow[e] * nbs[e];
            nbias[n] = a;
        }
    } else if (bid < PREP_CE) {
        // ---- convert_emb: 4 elems/thread, float4 -> bf16x4 ----
        bf16* ab8 = (bf16*)(ws + OFF_AB);
        bf16* mv8 = (bf16*)(ws + OFF_MV);
        const int i = ((bid - PREP_CW) * 256 + t) * 4;   // 0..153596
        const bool isab = i < 300 * 128;
        const float4 v = isab ? *(const float4*)(ab_emb + i)
                              : *(const float4*)(mv_emb + (i - 300 * 128));
        bf16x4 o = {(bf16)v.x, (bf16)v.y, (bf16)v.z, (bf16)v.w};
        if (isab) *(bf16x4*)(ab8 + i) = o;
        else *(bf16x4*)(mv8 + (i - 300 * 128)) = o;
    } else {
        // ---- pack MLP weight fragments (B-frag: lane n=l&15, k=(l>>4)*8+j) --
        bf16* W1f = (bf16*)(ws + OFF_W1F);
        bf16* W2f = (bf16*)(ws + OFF_W2F);
        bf16* Waf = (bf16*)(ws + OFF_WAF);
        for (int e = t; e < 8192; e += 256) {     // W1 (64x128), fid = nt*4+kt
            const int j = e & 7, ln = (e >> 3) & 63, fid = e >> 9;
            const int kt = fid & 3, nt = fid >> 2;
            const int n = nt * 16 + (ln & 15);
            const int k = kt * 32 + (ln >> 4) * 8 + j;
            W1f[e] = (bf16)W1[n * 128 + k];
        }
        for (int e = t; e < 8192; e += 256) {     // W2 (128x64), fid = nt*2+kt
            const int j = e & 7, ln = (e >> 3) & 63, fid = e >> 9;
            const int kt = fid & 1, nt = fid >> 1;
            const int n = nt * 16 + (ln & 15);
            const int k = kt * 32 + (ln >> 4) * 8 + j;
            W2f[e] = (bf16)W2[n * 64 + k];
        }
        for (int e = t; e < 2048; e += 256) {     // Wa (9x128 zero-padded)
            const int j = e & 7, ln = (e >> 3) & 63, kt = e >> 9;
            const int n = ln & 15;
            const int k = kt * 32 + (ln >> 4) * 8 + j;
            Waf[e] = (n < 9) ? (bf16)Wa[n * 128 + k] : (bf16)0.f;
        }
    }
}

// ---------------------------------------------------------------------------
// Kernel 2: gpart[bz] = x @ Wcat.T partial  (x gathered on the fly)
// NEW: 64x128 block tile (was 128x128) to cut LDS 74 -> 53.5 KB and raise
// residency 2 -> 3 blocks/CU (3 independent barrier groups to hide the
// per-K-step vmcnt(0)+barrier drain). Same verified 2-barrier schedule,
// same XOR swizzle (all formulas depend only on row&7). Grid 64x4x4 = 1024
// blocks, plain dispatch (XCD pinning reverted: -5% due to L2 hot-banking).
// Per wave: 2 A-loads + 4 B-loads staged, acc 4x4, 16 MFMA/step.
// ---------------------------------------------------------------------------
__global__ __launch_bounds__(256, 3) void gemm_gates(
    const uint8_t* __restrict__ wsbase,
    const bf16* __restrict__ Wcat,
    const uint32_t* __restrict__ addrs,
    bf16* __restrict__ gpart) {
    __shared__ bf16 As[2][64 * 64];     // 2 x 8 KB
    __shared__ bf16 Bs[2][128 * 64];    // 2 x 16 KB
    __shared__ uint32_t adr[17][64];    // 4.25 KB

    const int tid = threadIdx.x;
    const int w = tid >> 6;       // wave 0..3
    const int lane = tid & 63;
    const int bm = blockIdx.x;    // 0..63
    const int bn = blockIdx.y;    // 0..3
    const int bz = blockIdx.z;    // 0..3
    const int kt_beg = bz * 31;
    const int kt_end = kt_beg + 31;

    // preload this block's (row, slot) offsets
    const int s0 = kt_beg >> 1;
    const int ns = ((kt_end - 1) >> 1) - s0 + 1;   // <= 17
    for (int i = tid; i < ns * 64; i += 256) {
        adr[i >> 6][i & 63] =
            addrs[(size_t)(bm * 64 + (i & 63)) * 64 + s0 + (i >> 6)];
    }

    const int r_l = lane >> 3;                  // staging row within 8-row group
    const int sc16 = ((lane & 7) ^ r_l) * 16;   // XOR-swizzled 16B chunk (bytes)

    const int wn = w & 1;         // n-half: cols wn*64 .. wn*64+63
    const int wk = w >> 1;        // k-slice: elems wk*32 .. wk*32+31 of each BK
    const int n0 = wn * 64;
    const int kk8 = wk * 4 + (lane >> 4);       // global column chunk for frags
    const int fl = lane & 15;

    f32x4 acc[4][4];
#pragma unroll
    for (int i = 0; i < 4; ++i)
#pragma unroll
        for (int j = 0; j < 4; ++j)
#pragma unroll
            for (int r = 0; r < 4; ++r) acc[i][j][r] = 0.f;

    __syncthreads();  // adr visible

    auto stage = [&](int kt, int pb) {
        const int k0 = kt * 64;
        const int sl = (kt >> 1) - s0;
        const int hb = (kt & 1) * 128;
#pragma unroll
        for (int j = 0; j < 2; ++j) {           // A: 64 rows = 8 groups
            const int row = (w * 2 + j) * 8 + r_l;
            const uint8_t* gsrc = wsbase + adr[sl][row] + hb + sc16;
            async16(gsrc, (void*)&As[pb][((w * 2 + j) * 64 + lane) * 8]);
        }
#pragma unroll
        for (int j = 0; j < 4; ++j) {           // B: 128 rows = 16 groups
            const int row = (w * 4 + j) * 8 + r_l;
            const bf16* gsrc = Wcat + (size_t)(bn * 128 + row) * KTOT + k0 + (sc16 >> 1);
            async16(gsrc, (void*)&Bs[pb][((w * 4 + j) * 64 + lane) * 8]);
        }
    };

    stage(kt_beg, 0);   // prologue into buffer 0

    for (int kt = kt_beg; kt < kt_end; ++kt) {
        const int pb = (kt - kt_beg) & 1;
        __syncthreads();
        if (kt + 1 < kt_end) stage(kt + 1, pb ^ 1);

        const bf16* Ab = &As[pb][0];
        const bf16* Bb = &Bs[pb][0];

        bf16x8 bfr[4];
#pragma unroll
        for (int tj = 0; tj < 4; ++tj) {
            const int n = n0 + tj * 16 + fl;
            bfr[tj] = *(const bf16x8*)&Bb[n * 64 + ((kk8 ^ (n & 7)) * 8)];
        }
#pragma unroll
        for (int ti = 0; ti < 4; ++ti) {
            const int m = ti * 16 + fl;
            const bf16x8 af = *(const bf16x8*)&Ab[m * 64 + ((kk8 ^ (m & 7)) * 8)];
#pragma unroll
            for (int tj = 0; tj < 4; ++tj)
                acc[ti][tj] = __builtin_amdgcn_mfma_f32_16x16x32_bf16(
                    af, bfr[tj], acc[ti][tj], 0, 0, 0);
        }
    }

    // ---- reduce wk-partials through LDS (As/Bs are dead now) ----
    __syncthreads();
    // per n-half: 4*4 frag * 4 reg * 64 lanes * 4B = 16 KB
    float* red = (wn == 0) ? (float*)&As[0][0] : (float*)&Bs[0][0];
    if (wk == 1) {
#pragma unroll
        for (int ti = 0; ti < 4; ++ti)
#pragma unroll
            for (int tj = 0; tj < 4; ++tj)
#pragma unroll
                for (int r = 0; r < 4; ++r)
                    red[((ti * 4 + tj) * 4 + r) * 64 + lane] = acc[ti][tj][r];
    }
    __syncthreads();

    if (wk == 0) {
        bf16* gdst = gpart + (size_t)bz * BATCH * NG;
        const int mlo = (lane >> 4) * 4;
#pragma unroll
        for (int ti = 0; ti < 4; ++ti)
#pragma unroll
            for (int tj = 0; tj < 4; ++tj) {
                const int mg = bm * 64 + ti * 16 + mlo;
                const int ng = bn * 128 + n0 + tj * 16 + fl;
                bf16* dst = gdst + (size_t)mg * NG + ng;
#pragma unroll
                for (int r = 0; r < 4; ++r)
                    dst[(size_t)r * NG] = (bf16)(
                        acc[ti][tj][r] + red[((ti * 4 + tj) * 4 + r) * 64 + lane]);
            }
    }
}

// ---------------------------------------------------------------------------
// Kernel 3: fused tail = split-K reduce + LSTM pointwise + MLP head.
// (verbatim from round-3 passing version)
// ---------------------------------------------------------------------------
__global__ __launch_bounds__(256) void tail(
    const bf16* __restrict__ gpart,
    const float* __restrict__ bih, const float* __restrict__ bhh,
    const float* __restrict__ nbias, const float* __restrict__ c0,
    const float* __restrict__ mask,
    const bf16* __restrict__ W1f, const bf16* __restrict__ W2f,
    const bf16* __restrict__ Waf,
    const float* __restrict__ b1, const float* __restrict__ b2,
    const float* __restrict__ ba,
    float* __restrict__ out) {
    __shared__ bf16 hS[16 * 128];    // 4 KB
    __shared__ bf16 uS[16 * 64];     // 2 KB
    __shared__ bf16 fS[16 * 128];    // 4 KB

    const int t = threadIdx.x;
    const int bid = blockIdx.x;
    const int b0 = bid * 16;

    // --- phase A: gate reduction + LSTM, 8 units/thread ---
    {
        const int r = t >> 4;               // row 0..15
        const int uc = (t & 15) * 8;        // unit chunk
        const int b = b0 + r;

        float gv[4][8];
#pragma unroll
        for (int q = 0; q < 4; ++q)
#pragma unroll
            for (int hh = 0; hh < 2; ++hh) {
                const f32x4 va = *(const f32x4*)(bih + q * 128 + uc + hh * 4);
                const f32x4 vb = *(const f32x4*)(bhh + q * 128 + uc + hh * 4);
                const f32x4 vn = *(const f32x4*)(nbias + q * 128 + uc + hh * 4);
#pragma unroll
                for (int j = 0; j < 4; ++j)
                    gv[q][hh * 4 + j] = va[j] + vb[j] + vn[j];
            }
#pragma unroll
        for (int z = 0; z < SPLITK; ++z) {
            const bf16* gz = gpart + ((size_t)z * BATCH + b) * NG;
#pragma unroll
            for (int q = 0; q < 4; ++q) {
                const bf16x8 v = *(const bf16x8*)(gz + q * 128 + uc);
#pragma unroll
                for (int j = 0; j < 8; ++j) gv[q][j] += (float)v[j];
            }
        }

        const f32x4 c0a = *(const f32x4*)(c0 + (size_t)b * LH + uc);
        const f32x4 c0b = *(const f32x4*)(c0 + (size_t)b * LH + uc + 4);
        float h1v[8], c1v[8];
        bf16x8 hv8;
#pragma unroll
        for (int j = 0; j < 8; ++j) {
            const float iv = 1.f / (1.f + __expf(-gv[0][j]));
            const float fv = 1.f / (1.f + __expf(-gv[1][j]));
            const float gg = tanhf(gv[2][j]);
            const float ov = 1.f / (1.f + __expf(-gv[3][j]));
            const float c0j = (j < 4) ? c0a[j] : c0b[j - 4];
            const float c1 = fv * c0j + iv * gg;
            const float h1 = ov * tanhf(c1);
            c1v[j] = c1;
            h1v[j] = h1;
            hv8[j] = (bf16)h1;
        }
        *(bf16x8*)&hS[r * 128 + uc] = hv8;
        *(f32x4*)(out + O_H1 + (size_t)b * LH + uc) = *(const f32x4*)&h1v[0];
        *(f32x4*)(out + O_H1 + (size_t)b * LH + uc + 4) = *(const f32x4*)&h1v[4];
        *(f32x4*)(out + O_C1 + (size_t)b * LH + uc) = *(const f32x4*)&c1v[0];
        *(f32x4*)(out + O_C1 + (size_t)b * LH + uc + 4) = *(const f32x4*)&c1v[4];
    }
    __syncthreads();

    // --- phase B: MLP head on wave 0 ---
    const int nl = t & 15, kg = (t & 63) >> 4;

    if (t < 64) {
        bf16x8 ah[4];
#pragma unroll
        for (int kt = 0; kt < 4; ++kt)
            ah[kt] = *(const bf16x8*)&hS[nl * 128 + kt * 32 + kg * 8];
#pragma unroll
        for (int nt = 0; nt < 4; ++nt) {
            f32x4 a = {0.f, 0.f, 0.f, 0.f};
#pragma unroll
            for (int kt = 0; kt < 4; ++kt)
                a = __builtin_amdgcn_mfma_f32_16x16x32_bf16(
                    ah[kt], *(const bf16x8*)&W1f[((nt * 4 + kt) * 64 + t) * 8],
                    a, 0, 0, 0);
            const int n = nt * 16 + nl;
            const float bb = b1[n];
#pragma unroll
            for (int rr = 0; rr < 4; ++rr)
                uS[(kg * 4 + rr) * 64 + n] = (bf16)fmaxf(a[rr] + bb, 0.f);
        }
    }
    __syncthreads();

    if (t < 64) {
        bf16x8 au[2];
#pragma unroll
        for (int kt = 0; kt < 2; ++kt)
            au[kt] = *(const bf16x8*)&uS[nl * 64 + kt * 32 + kg * 8];
#pragma unroll
        for (int nt = 0; nt < 8; ++nt) {
            f32x4 a = {0.f, 0.f, 0.f, 0.f};
#pragma unroll
            for (int kt = 0; kt < 2; ++kt)
                a = __builtin_amdgcn_mfma_f32_16x16x32_bf16(
                    au[kt], *(const bf16x8*)&W2f[((nt * 2 + kt) * 64 + t) * 8],
                    a, 0, 0, 0);
            const int n = nt * 16 + nl;
            const float bb = b2[n];
#pragma unroll
            for (int rr = 0; rr < 4; ++rr)
                fS[(kg * 4 + rr) * 128 + n] = (bf16)(a[rr] + bb);
        }
    }
    __syncthreads();

    if (t < 64) {
        bf16x8 afr[4];
#pragma unroll
        for (int kt = 0; kt < 4; ++kt)
            afr[kt] = *(const bf16x8*)&fS[nl * 128 + kt * 32 + kg * 8];

        f32x4 lg4 = {0.f, 0.f, 0.f, 0.f};
#pragma unroll
        for (int kt = 0; kt < 4; ++kt)
            lg4 = __builtin_amdgcn_mfma_f32_16x16x32_bf16(
                afr[kt], *(const bf16x8*)&Waf[(kt * 64 + t) * 8], lg4, 0, 0, 0);

        const float bav = (nl < 9) ? ba[nl] : 0.f;

#pragma unroll
        for (int rr = 0; rr < 4; ++rr) {
            const int b = b0 + kg * 4 + rr;
            float lg = (nl < 9) ? lg4[rr] + bav : -1e30f;
            float mx = lg;
#pragma unroll
            for (int off = 1; off < 16; off <<= 1)
                mx = fmaxf(mx, __shfl_xor(mx, off, 64));
            const float e = (nl < 9) ? __expf(lg - mx) : 0.f;
            const float mv = (nl < 9) ? mask[(size_t)b * 9 + nl] : 0.f;
            float tot = e, ms = e * mv;
#pragma unroll
            for (int off = 1; off < 16; off <<= 1) {
                tot += __shfl_xor(tot, off, 64);
                ms += __shfl_xor(ms, off, 64);
            }
            if (nl < 9)
                out[(size_t)b * 9 + nl] = (ms > 0.f) ? e * mv / ms : e / tot;
        }
    }
}

// ---------------------------------------------------------------------------
extern "C" void kernel_launch(void* const* d_in, const int* in_sizes, int n_in,
                              void* d_out, int out_size, void* d_ws, size_t ws_size,
                              hipStream_t stream) {
    const int* ab_ids = (const int*)d_in[0];
    const int* mv_ids = (const int*)d_in[1];
    const float* numerical = (const float*)d_in[2];
    const float* mask = (const float*)d_in[3];
    const float* h0 = (const float*)d_in[4];
    const float* c0 = (const float*)d_in[5];
    const float* ab_emb = (const float*)d_in[6];
    const float* mv_emb = (const float*)d_in[7];
    const float* numW = (const float*)d_in[8];
    const float* numb = (const float*)d_in[9];
    const float* Wih = (const float*)d_in[10];
    const float* Whh = (const float*)d_in[11];
    const float* bih = (const float*)d_in[12];
    const float* bhh = (const float*)d_in[13];
    const float* W1 = (const float*)d_in[14];
    const float* b1 = (const float*)d_in[15];
    const float* W2 = (const float*)d_in[16];
    const float* b2 = (const float*)d_in[17];
    const float* Wa = (const float*)d_in[18];
    const float* ba = (const float*)d_in[19];
    float* out = (float*)d_out;

    uint8_t* ws = (uint8_t*)d_ws;
    bf16* Wcat = (bf16*)(ws + OFF_WCAT);
    bf16* gpart = (bf16*)(ws + OFF_GPART);
    uint32_t* addrs = (uint32_t*)(ws + OFF_ADDR);
    bf16* W1f = (bf16*)(ws + OFF_W1F);
    bf16* W2f = (bf16*)(ws + OFF_W2F);
    bf16* Waf = (bf16*)(ws + OFF_WAF);
    float* nbias = (float*)(ws + OFF_NB);

    prep<<<PREP_TOT, 256, 0, stream>>>(
        ab_ids, mv_ids, numerical, h0, numW, numb, Wih, Whh, ab_emb, mv_emb,
        W1, W2, Wa, ws);
    gemm_gates<<<dim3(64, 4, 4), 256, 0, stream>>>(ws, Wcat, addrs, gpart);
    tail<<<BATCH / 16, 256, 0, stream>>>(gpart, bih, bhh, nbias, c0, mask,
                                         W1f, W2f, Waf, b1, b2, ba, out);
}

// Round 5
// 170.732 us; speedup vs baseline: 1.0743x; 1.0743x over previous
//
#include <hip/hip_runtime.h>
#include <hip/hip_bf16.h>
#include <stdint.h>
#include <stddef.h>

typedef __bf16 bf16;
typedef __bf16 bf16x4 __attribute__((ext_vector_type(4)));
typedef __bf16 bf16x8 __attribute__((ext_vector_type(8)));
typedef float f32x4 __attribute__((ext_vector_type(4)));

#define BATCH 4096
#define KIH 7808          // Wih K
#define KTOT 7936         // 62 slots * 128 (h0 appended)
#define NG 512            // 4*LH gates
#define LH 128
#define HD 64
#define ED 128
#define SPLITK 4

// workspace layout (byte offsets)
#define OFF_WCAT 0u                 //  8,126,464  bf16 Wcat[512][7936]
#define OFF_GPART 8126464u          // 16,777,216  bf16 gpart[4][4096][512]
#define OFF_XT   24903680u          //  2,097,152  bf16 xtail[4096][256]
#define OFF_AB   27000832u          //     76,800  bf16 ab8[300][128]
#define OFF_MV   27077632u          //    230,400  bf16 mv8[900][128]
#define OFF_ADDR 27308032u          //  1,048,576  u32 addrs[4096][64]
#define OFF_W1F  29405184u          //     16,384  bf16 W1 fragments
#define OFF_W2F  29421568u          //     16,384  bf16 W2 fragments
#define OFF_WAF  29437952u          //      4,096  bf16 Wa fragments
#define OFF_NB   29442048u          //      2,048  f32 nbias[512]
// end: 29,444,096 B

// out layout: probs[B*9] | h1[B*128] | c1[B*128]
#define O_H1 (BATCH * 9)
#define O_C1 (BATCH * 9 + BATCH * LH)

// prep grid partition
#define PREP_BP 2048                 // build_pre: 2 rows/block
#define PREP_CW (PREP_BP + 512)      // convert_w
#define PREP_CE (PREP_CW + 150)      // convert_emb (float4 x 256 x 150 = 153600)
#define PREP_TOT (PREP_CE + 1)       // + MLP fragment pack

// ---------------------------------------------------------------------------
typedef const __attribute__((address_space(1))) uint32_t* gas_ptr;
typedef __attribute__((address_space(3))) uint32_t* las_ptr;

__device__ __forceinline__ void async16(const void* g, void* l) {
    __builtin_amdgcn_global_load_lds((gas_ptr)g, (las_ptr)l, 16, 0, 0);
}

// ---------------------------------------------------------------------------
// Kernel 1: fused prep (verbatim from the verified version).
// ---------------------------------------------------------------------------
__global__ void prep(const int* __restrict__ ab_ids,
                     const int* __restrict__ mv_ids,
                     const float* __restrict__ numerical,
                     const float* __restrict__ h0,
                     const float* __restrict__ numW,
                     const float* __restrict__ numb,
                     const float* __restrict__ Wih,
                     const float* __restrict__ Whh,
                     const float* __restrict__ ab_emb,
                     const float* __restrict__ mv_emb,
                     const float* __restrict__ W1,
                     const float* __restrict__ W2,
                     const float* __restrict__ Wa,
                     uint8_t* __restrict__ ws) {
    const int bid = blockIdx.x;
    const int t = threadIdx.x;  // 0..255

    if (bid < PREP_BP) {
        // ---- build_pre: 2 rows per block; half-block (128 thr) per row ----
        bf16* xtail = (bf16*)(ws + OFF_XT);
        uint32_t* addrs = (uint32_t*)(ws + OFF_ADDR);
        const int h = t >> 7;            // row half 0/1
        const int th = t & 127;
        const int b = bid * 2 + h;

        __shared__ int ids[2][60];
        if (th < 60)
            ids[h][th] = (th < 12) ? ab_ids[b * 12 + th]
                                   : mv_ids[b * 48 + (th - 12)];

        const float v = (th < 84) ? numerical[(size_t)b * 84 + th] : 0.f;
        xtail[(size_t)b * 256 + th] = (bf16)v;
        xtail[(size_t)b * 256 + 128 + th] = (bf16)h0[(size_t)b * LH + th];
        __syncthreads();

        if (th < 64) {
            uint32_t off;
            if (th < 12) off = OFF_AB + (uint32_t)ids[h][th] * 256u;
            else if (th < 60) off = OFF_MV + (uint32_t)ids[h][th] * 256u;
            else if (th == 60) off = OFF_XT + (uint32_t)b * 512u;
            else if (th == 61) off = OFF_XT + (uint32_t)b * 512u + 256u;
            else off = OFF_XT;  // unused slots 62,63
            addrs[(size_t)b * 64 + th] = off;
        }
    } else if (bid < PREP_CW) {
        // ---- convert_w: cols [0,7680) direct; slot 60 = Wfold; then Whh ----
        bf16* Wcat = (bf16*)(ws + OFF_WCAT);
        float* nbias = (float*)(ws + OFF_NB);
        const int n = bid - PREP_BP;

        __shared__ float wrow[128];   // Wih[n][7680..7808)
        __shared__ float nbs[128];
        if (t < 128) wrow[t] = Wih[(size_t)n * KIH + 7680 + t];
        else nbs[t - 128] = numb[t - 128];
        __syncthreads();

        const float* src_ih = Wih + (size_t)n * KIH;
        bf16* dst = Wcat + (size_t)n * KTOT;
        for (int k4 = t; k4 < 1920; k4 += 256) {   // 7680/4
            const int k = k4 * 4;
            const float4 v = *(const float4*)(src_ih + k);
            bf16x4 o = {(bf16)v.x, (bf16)v.y, (bf16)v.z, (bf16)v.w};
            *(bf16x4*)(dst + k) = o;
        }
        if (t < 84) {
            // Wfold[n][t] = sum_e Wih[n][7680+e] * numW[e][t]
            float acc = 0.f;
#pragma unroll 4
            for (int e = 0; e < 128; ++e)
                acc += wrow[e] * numW[e * 84 + t];
            dst[7680 + t] = (bf16)acc;
        } else if (t < 128) {
            dst[7680 + t] = (bf16)0.f;     // padding cols (x is zero there too)
        } else {
            const int tt = t - 128;
            dst[KIH + tt] = (bf16)Whh[(size_t)n * LH + tt];
        }
        if (t == 255) {
            float a = 0.f;
#pragma unroll 4
            for (int e = 0; e < 128; ++e) a += wrow[e] * nbs[e];
            nbias[n] = a;
        }
    } else if (bid < PREP_CE) {
        // ---- convert_emb: 4 elems/thread, float4 -> bf16x4 ----
        bf16* ab8 = (bf16*)(ws + OFF_AB);
        bf16* mv8 = (bf16*)(ws + OFF_MV);
        const int i = ((bid - PREP_CW) * 256 + t) * 4;   // 0..153596
        const bool isab = i < 300 * 128;
        const float4 v = isab ? *(const float4*)(ab_emb + i)
                              : *(const float4*)(mv_emb + (i - 300 * 128));
        bf16x4 o = {(bf16)v.x, (bf16)v.y, (bf16)v.z, (bf16)v.w};
        if (isab) *(bf16x4*)(ab8 + i) = o;
        else *(bf16x4*)(mv8 + (i - 300 * 128)) = o;
    } else {
        // ---- pack MLP weight fragments (B-frag: lane n=l&15, k=(l>>4)*8+j) --
        bf16* W1f = (bf16*)(ws + OFF_W1F);
        bf16* W2f = (bf16*)(ws + OFF_W2F);
        bf16* Waf = (bf16*)(ws + OFF_WAF);
        for (int e = t; e < 8192; e += 256) {     // W1 (64x128), fid = nt*4+kt
            const int j = e & 7, ln = (e >> 3) & 63, fid = e >> 9;
            const int kt = fid & 3, nt = fid >> 2;
            const int n = nt * 16 + (ln & 15);
            const int k = kt * 32 + (ln >> 4) * 8 + j;
            W1f[e] = (bf16)W1[n * 128 + k];
        }
        for (int e = t; e < 8192; e += 256) {     // W2 (128x64), fid = nt*2+kt
            const int j = e & 7, ln = (e >> 3) & 63, fid = e >> 9;
            const int kt = fid & 1, nt = fid >> 1;
            const int n = nt * 16 + (ln & 15);
            const int k = kt * 32 + (ln >> 4) * 8 + j;
            W2f[e] = (bf16)W2[n * 64 + k];
        }
        for (int e = t; e < 2048; e += 256) {     // Wa (9x128 zero-padded)
            const int j = e & 7, ln = (e >> 3) & 63, kt = e >> 9;
            const int n = ln & 15;
            const int k = kt * 32 + (ln >> 4) * 8 + j;
            Waf[e] = (n < 9) ? (bf16)Wa[n * 128 + k] : (bf16)0.f;
        }
    }
}

// ---------------------------------------------------------------------------
// Kernel 2: gpart[bz] = x @ Wcat.T partial  (x gathered on the fly)
// NEW (T3+T4): 128x128 tile, BK=32, 4-deep LDS ring (4x16KB + adr 8KB =
// 72KB -> 2 blocks/CU), loads staged 2 tiles ahead, ONE raw s_barrier per
// step, counted s_waitcnt vmcnt(8) (never 0 in main loop; peeled 4->0
// epilogue). No wk-split: each wave owns a 64x64 output quadrant over full
// K-depth -> no LDS reduction epilogue. Read-side XOR swizzle kept via
// inverse-swizzled global source + linear LDS dest (rule #21).
// Effective streams/CU = 2 blocks x 2 tiles in flight = 4.
// ---------------------------------------------------------------------------
__global__ __launch_bounds__(256, 2) void gemm_gates(
    const uint8_t* __restrict__ wsbase,
    const bf16* __restrict__ Wcat,
    const uint32_t* __restrict__ addrs,
    bf16* __restrict__ gpart) {
    __shared__ bf16 As[4][128 * 32];    // 4 x 8 KB
    __shared__ bf16 Bs[4][128 * 32];    // 4 x 8 KB
    __shared__ uint32_t adr[16][128];   // 8 KB

    const int tid = threadIdx.x;
    const int w = tid >> 6;       // wave 0..3
    const int lane = tid & 63;
    const int bm = blockIdx.x;    // 0..31
    const int bn = blockIdx.y;    // 0..3
    const int bz = blockIdx.z;    // 0..3

    const int NS = 62;                 // K-steps of 32 per bz
    const int kt_beg = bz * NS;        // global 32-elem step index

    // preload this block's (row, slot) offsets; slots are 128-elem (256B)
    const int s0 = kt_beg >> 2;
    const int ns = ((kt_beg + NS - 1) >> 2) - s0 + 1;   // = 16 for all bz
    for (int i = tid; i < ns * 128; i += 256) {
        adr[i >> 7][i & 127] =
            addrs[(size_t)(bm * 128 + (i & 127)) * 64 + s0 + (i >> 7)];
    }

    const int wm = w >> 1;        // m-half: rows wm*64 .. +63
    const int wn = w & 1;         // n-half: cols wn*64 .. +63
    const int kg = lane >> 4;     // 0..3 k-chunk (8 elems) within BK=32
    const int fl = lane & 15;

    // staging decomposition: lane l covers row rl = l>>2 (of 16), chunk l&3
    const int rl = lane >> 2;                      // 0..15
    const int csw = (lane & 3) ^ (rl & 3);         // inverse-swizzled src chunk

    f32x4 acc[4][4];
#pragma unroll
    for (int i = 0; i < 4; ++i)
#pragma unroll
        for (int j = 0; j < 4; ++j)
#pragma unroll
            for (int r = 0; r < 4; ++r) acc[i][j][r] = 0.f;

    __syncthreads();  // adr visible

    // stage step i (local) into ring buffer pb. 4 async16 per wave.
    auto stage = [&](int i, int pb) {
        const int kt = kt_beg + i;
        const int sl = (kt >> 2) - s0;
        const int qoff = (kt & 3) * 64;            // byte offset in 256B slot
        const int k0 = kt * 32;                    // elem offset in Wcat row
#pragma unroll
        for (int j = 0; j < 2; ++j) {              // A: rows (w*2+j)*16 + rl
            const int row = (w * 2 + j) * 16 + rl;
            const uint8_t* ga = wsbase + adr[sl][row] + qoff + csw * 16;
            async16(ga, (void*)&As[pb][(row * 4 + (lane & 3)) * 8]);
        }
#pragma unroll
        for (int j = 0; j < 2; ++j) {              // B: same row pattern
            const int row = (w * 2 + j) * 16 + rl;
            const bf16* gb =
                Wcat + (size_t)(bn * 128 + row) * KTOT + k0 + csw * 8;
            async16(gb, (void*)&Bs[pb][(row * 4 + (lane & 3)) * 8]);
        }
    };

    auto compute = [&](int pb) {
        const bf16* Ab = &As[pb][0];
        const bf16* Bb = &Bs[pb][0];
        bf16x8 bfr[4], afr[4];
#pragma unroll
        for (int tj = 0; tj < 4; ++tj) {
            const int n = wn * 64 + tj * 16 + fl;
            bfr[tj] = *(const bf16x8*)&Bb[n * 32 + ((kg ^ (n & 3)) * 8)];
        }
#pragma unroll
        for (int ti = 0; ti < 4; ++ti) {
            const int m = wm * 64 + ti * 16 + fl;
            afr[ti] = *(const bf16x8*)&Ab[m * 32 + ((kg ^ (m & 3)) * 8)];
        }
#pragma unroll
        for (int ti = 0; ti < 4; ++ti)
#pragma unroll
            for (int tj = 0; tj < 4; ++tj)
                acc[ti][tj] = __builtin_amdgcn_mfma_f32_16x16x32_bf16(
                    afr[ti], bfr[tj], acc[ti][tj], 0, 0, 0);
    };

    // prologue: 2 tiles in flight
    stage(0, 0);
    stage(1, 1);

    // main loop: steps 0 .. NS-3 with vmcnt(8)
    for (int i = 0; i < NS - 2; ++i) {
        stage(i + 2, (i + 2) & 3);
        asm volatile("s_waitcnt vmcnt(8)" ::: "memory");   // tile i landed
        __builtin_amdgcn_sched_barrier(0);
        __builtin_amdgcn_s_barrier();
        compute(i & 3);
    }
    // peeled epilogue: i = NS-2 (wait 4), i = NS-1 (wait 0)
    {
        asm volatile("s_waitcnt vmcnt(4)" ::: "memory");
        __builtin_amdgcn_sched_barrier(0);
        __builtin_amdgcn_s_barrier();
        compute((NS - 2) & 3);

        asm volatile("s_waitcnt vmcnt(0)" ::: "memory");
        __builtin_amdgcn_sched_barrier(0);
        __builtin_amdgcn_s_barrier();
        compute((NS - 1) & 3);
    }

    // ---- C-write: each wave owns its 64x64 quadrant (no reduction) ----
    bf16* gdst = gpart + (size_t)bz * BATCH * NG;
    const int mlo = (lane >> 4) * 4;
#pragma unroll
    for (int ti = 0; ti < 4; ++ti)
#pragma unroll
        for (int tj = 0; tj < 4; ++tj) {
            const int mg = bm * 128 + wm * 64 + ti * 16 + mlo;
            const int ng = bn * 128 + wn * 64 + tj * 16 + fl;
            bf16* dst = gdst + (size_t)mg * NG + ng;
#pragma unroll
            for (int r = 0; r < 4; ++r)
                dst[(size_t)r * NG] = (bf16)acc[ti][tj][r];
        }
}

// ---------------------------------------------------------------------------
// Kernel 3: fused tail = split-K reduce + LSTM pointwise + MLP head.
// (verbatim from round-3 passing version)
// ---------------------------------------------------------------------------
__global__ __launch_bounds__(256) void tail(
    const bf16* __restrict__ gpart,
    const float* __restrict__ bih, const float* __restrict__ bhh,
    const float* __restrict__ nbias, const float* __restrict__ c0,
    const float* __restrict__ mask,
    const bf16* __restrict__ W1f, const bf16* __restrict__ W2f,
    const bf16* __restrict__ Waf,
    const float* __restrict__ b1, const float* __restrict__ b2,
    const float* __restrict__ ba,
    float* __restrict__ out) {
    __shared__ bf16 hS[16 * 128];    // 4 KB
    __shared__ bf16 uS[16 * 64];     // 2 KB
    __shared__ bf16 fS[16 * 128];    // 4 KB

    const int t = threadIdx.x;
    const int bid = blockIdx.x;
    const int b0 = bid * 16;

    // --- phase A: gate reduction + LSTM, 8 units/thread ---
    {
        const int r = t >> 4;               // row 0..15
        const int uc = (t & 15) * 8;        // unit chunk
        const int b = b0 + r;

        float gv[4][8];
#pragma unroll
        for (int q = 0; q < 4; ++q)
#pragma unroll
            for (int hh = 0; hh < 2; ++hh) {
                const f32x4 va = *(const f32x4*)(bih + q * 128 + uc + hh * 4);
                const f32x4 vb = *(const f32x4*)(bhh + q * 128 + uc + hh * 4);
                const f32x4 vn = *(const f32x4*)(nbias + q * 128 + uc + hh * 4);
#pragma unroll
                for (int j = 0; j < 4; ++j)
                    gv[q][hh * 4 + j] = va[j] + vb[j] + vn[j];
            }
#pragma unroll
        for (int z = 0; z < SPLITK; ++z) {
            const bf16* gz = gpart + ((size_t)z * BATCH + b) * NG;
#pragma unroll
            for (int q = 0; q < 4; ++q) {
                const bf16x8 v = *(const bf16x8*)(gz + q * 128 + uc);
#pragma unroll
                for (int j = 0; j < 8; ++j) gv[q][j] += (float)v[j];
            }
        }

        const f32x4 c0a = *(const f32x4*)(c0 + (size_t)b * LH + uc);
        const f32x4 c0b = *(const f32x4*)(c0 + (size_t)b * LH + uc + 4);
        float h1v[8], c1v[8];
        bf16x8 hv8;
#pragma unroll
        for (int j = 0; j < 8; ++j) {
            const float iv = 1.f / (1.f + __expf(-gv[0][j]));
            const float fv = 1.f / (1.f + __expf(-gv[1][j]));
            const float gg = tanhf(gv[2][j]);
            const float ov = 1.f / (1.f + __expf(-gv[3][j]));
            const float c0j = (j < 4) ? c0a[j] : c0b[j - 4];
            const float c1 = fv * c0j + iv * gg;
            const float h1 = ov * tanhf(c1);
            c1v[j] = c1;
            h1v[j] = h1;
            hv8[j] = (bf16)h1;
        }
        *(bf16x8*)&hS[r * 128 + uc] = hv8;
        *(f32x4*)(out + O_H1 + (size_t)b * LH + uc) = *(const f32x4*)&h1v[0];
        *(f32x4*)(out + O_H1 + (size_t)b * LH + uc + 4) = *(const f32x4*)&h1v[4];
        *(f32x4*)(out + O_C1 + (size_t)b * LH + uc) = *(const f32x4*)&c1v[0];
        *(f32x4*)(out + O_C1 + (size_t)b * LH + uc + 4) = *(const f32x4*)&c1v[4];
    }
    __syncthreads();

    // --- phase B: MLP head on wave 0 ---
    const int nl = t & 15, kg = (t & 63) >> 4;

    if (t < 64) {
        bf16x8 ah[4];
#pragma unroll
        for (int kt = 0; kt < 4; ++kt)
            ah[kt] = *(const bf16x8*)&hS[nl * 128 + kt * 32 + kg * 8];
#pragma unroll
        for (int nt = 0; nt < 4; ++nt) {
            f32x4 a = {0.f, 0.f, 0.f, 0.f};
#pragma unroll
            for (int kt = 0; kt < 4; ++kt)
                a = __builtin_amdgcn_mfma_f32_16x16x32_bf16(
                    ah[kt], *(const bf16x8*)&W1f[((nt * 4 + kt) * 64 + t) * 8],
                    a, 0, 0, 0);
            const int n = nt * 16 + nl;
            const float bb = b1[n];
#pragma unroll
            for (int rr = 0; rr < 4; ++rr)
                uS[(kg * 4 + rr) * 64 + n] = (bf16)fmaxf(a[rr] + bb, 0.f);
        }
    }
    __syncthreads();

    if (t < 64) {
        bf16x8 au[2];
#pragma unroll
        for (int kt = 0; kt < 2; ++kt)
            au[kt] = *(const bf16x8*)&uS[nl * 64 + kt * 32 + kg * 8];
#pragma unroll
        for (int nt = 0; nt < 8; ++nt) {
            f32x4 a = {0.f, 0.f, 0.f, 0.f};
#pragma unroll
            for (int kt = 0; kt < 2; ++kt)
                a = __builtin_amdgcn_mfma_f32_16x16x32_bf16(
                    au[kt], *(const bf16x8*)&W2f[((nt * 2 + kt) * 64 + t) * 8],
                    a, 0, 0, 0);
            const int n = nt * 16 + nl;
            const float bb = b2[n];
#pragma unroll
            for (int rr = 0; rr < 4; ++rr)
                fS[(kg * 4 + rr) * 128 + n] = (bf16)(a[rr] + bb);
        }
    }
    __syncthreads();

    if (t < 64) {
        bf16x8 afr[4];
#pragma unroll
        for (int kt = 0; kt < 4; ++kt)
            afr[kt] = *(const bf16x8*)&fS[nl * 128 + kt * 32 + kg * 8];

        f32x4 lg4 = {0.f, 0.f, 0.f, 0.f};
#pragma unroll
        for (int kt = 0; kt < 4; ++kt)
            lg4 = __builtin_amdgcn_mfma_f32_16x16x32_bf16(
                afr[kt], *(const bf16x8*)&Waf[(kt * 64 + t) * 8], lg4, 0, 0, 0);

        const float bav = (nl < 9) ? ba[nl] : 0.f;

#pragma unroll
        for (int rr = 0; rr < 4; ++rr) {
            const int b = b0 + kg * 4 + rr;
            float lg = (nl < 9) ? lg4[rr] + bav : -1e30f;
            float mx = lg;
#pragma unroll
            for (int off = 1; off < 16; off <<= 1)
                mx = fmaxf(mx, __shfl_xor(mx, off, 64));
            const float e = (nl < 9) ? __expf(lg - mx) : 0.f;
            const float mv = (nl < 9) ? mask[(size_t)b * 9 + nl] : 0.f;
            float tot = e, ms = e * mv;
#pragma unroll
            for (int off = 1; off < 16; off <<= 1) {
                tot += __shfl_xor(tot, off, 64);
                ms += __shfl_xor(ms, off, 64);
            }
            if (nl < 9)
                out[(size_t)b * 9 + nl] = (ms > 0.f) ? e * mv / ms : e / tot;
        }
    }
}

// ---------------------------------------------------------------------------
extern "C" void kernel_launch(void* const* d_in, const int* in_sizes, int n_in,
                              void* d_out, int out_size, void* d_ws, size_t ws_size,
                              hipStream_t stream) {
    const int* ab_ids = (const int*)d_in[0];
    const int* mv_ids = (const int*)d_in[1];
    const float* numerical = (const float*)d_in[2];
    const float* mask = (const float*)d_in[3];
    const float* h0 = (const float*)d_in[4];
    const float* c0 = (const float*)d_in[5];
    const float* ab_emb = (const float*)d_in[6];
    const float* mv_emb = (const float*)d_in[7];
    const float* numW = (const float*)d_in[8];
    const float* numb = (const float*)d_in[9];
    const float* Wih = (const float*)d_in[10];
    const float* Whh = (const float*)d_in[11];
    const float* bih = (const float*)d_in[12];
    const float* bhh = (const float*)d_in[13];
    const float* W1 = (const float*)d_in[14];
    const float* b1 = (const float*)d_in[15];
    const float* W2 = (const float*)d_in[16];
    const float* b2 = (const float*)d_in[17];
    const float* Wa = (const float*)d_in[18];
    const float* ba = (const float*)d_in[19];
    float* out = (float*)d_out;

    uint8_t* ws = (uint8_t*)d_ws;
    bf16* Wcat = (bf16*)(ws + OFF_WCAT);
    bf16* gpart = (bf16*)(ws + OFF_GPART);
    uint32_t* addrs = (uint32_t*)(ws + OFF_ADDR);
    bf16* W1f = (bf16*)(ws + OFF_W1F);
    bf16* W2f = (bf16*)(ws + OFF_W2F);
    bf16* Waf = (bf16*)(ws + OFF_WAF);
    float* nbias = (float*)(ws + OFF_NB);

    prep<<<PREP_TOT, 256, 0, stream>>>(
        ab_ids, mv_ids, numerical, h0, numW, numb, Wih, Whh, ab_emb, mv_emb,
        W1, W2, Wa, ws);
    gemm_gates<<<dim3(32, 4, 4), 256, 0, stream>>>(ws, Wcat, addrs, gpart);
    tail<<<BATCH / 16, 256, 0, stream>>>(gpart, bih, bhh, nbias, c0, mask,
                                         W1f, W2f, Waf, b1, b2, ba, out);
}

// Round 7
// 167.249 us; speedup vs baseline: 1.0966x; 1.0208x over previous
//
#include <hip/hip_runtime.h>
#include <hip/hip_bf16.h>
#include <stdint.h>
#include <stddef.h>

typedef __bf16 bf16;
typedef __bf16 bf16x4 __attribute__((ext_vector_type(4)));
typedef __bf16 bf16x8 __attribute__((ext_vector_type(8)));
typedef float f32x4 __attribute__((ext_vector_type(4)));

#define BATCH 4096
#define KIH 7808          // Wih K
#define KTOT 7936         // 62 slots * 128 (h0 appended)
#define NG 512            // 4*LH gates
#define LH 128
#define HD 64
#define ED 128
#define SPLITK 4

// workspace layout (byte offsets)
#define OFF_WCAT 0u                 //  8,126,464  bf16 Wcat[512][7936]
#define OFF_GPART 8126464u          // 16,777,216  bf16 gpart[4][4096][512]
#define OFF_XT   24903680u          //  2,097,152  bf16 xtail[4096][256]
#define OFF_AB   27000832u          //     76,800  bf16 ab8[300][128]
#define OFF_MV   27077632u          //    230,400  bf16 mv8[900][128]
#define OFF_ADDR 27308032u          //  1,048,576  u32 addrs[4096][64]
#define OFF_W1F  29405184u          //     16,384  bf16 W1 fragments
#define OFF_W2F  29421568u          //     16,384  bf16 W2 fragments
#define OFF_WAF  29437952u          //      4,096  bf16 Wa fragments
#define OFF_NB   29442048u          //      2,048  f32 nbias[512]
// end: 29,444,096 B

// out layout: probs[B*9] | h1[B*128] | c1[B*128]
#define O_H1 (BATCH * 9)
#define O_C1 (BATCH * 9 + BATCH * LH)

// prep grid partition
#define PREP_BP 2048                 // build_pre: 2 rows/block
#define PREP_CW (PREP_BP + 512)      // convert_w
#define PREP_CE (PREP_CW + 150)      // convert_emb (float4 x 256 x 150 = 153600)
#define PREP_TOT (PREP_CE + 1)       // + MLP fragment pack

// ---------------------------------------------------------------------------
typedef const __attribute__((address_space(1))) uint32_t* gas_ptr;
typedef __attribute__((address_space(3))) uint32_t* las_ptr;

__device__ __forceinline__ void async16(const void* g, void* l) {
    __builtin_amdgcn_global_load_lds((gas_ptr)g, (las_ptr)l, 16, 0, 0);
}

// ---------------------------------------------------------------------------
// Kernel 1: fused prep (verbatim from the verified version).
// ---------------------------------------------------------------------------
__global__ void prep(const int* __restrict__ ab_ids,
                     const int* __restrict__ mv_ids,
                     const float* __restrict__ numerical,
                     const float* __restrict__ h0,
                     const float* __restrict__ numW,
                     const float* __restrict__ numb,
                     const float* __restrict__ Wih,
                     const float* __restrict__ Whh,
                     const float* __restrict__ ab_emb,
                     const float* __restrict__ mv_emb,
                     const float* __restrict__ W1,
                     const float* __restrict__ W2,
                     const float* __restrict__ Wa,
                     uint8_t* __restrict__ ws) {
    const int bid = blockIdx.x;
    const int t = threadIdx.x;  // 0..255

    if (bid < PREP_BP) {
        // ---- build_pre: 2 rows per block; half-block (128 thr) per row ----
        bf16* xtail = (bf16*)(ws + OFF_XT);
        uint32_t* addrs = (uint32_t*)(ws + OFF_ADDR);
        const int h = t >> 7;            // row half 0/1
        const int th = t & 127;
        const int b = bid * 2 + h;

        __shared__ int ids[2][60];
        if (th < 60)
            ids[h][th] = (th < 12) ? ab_ids[b * 12 + th]
                                   : mv_ids[b * 48 + (th - 12)];

        const float v = (th < 84) ? numerical[(size_t)b * 84 + th] : 0.f;
        xtail[(size_t)b * 256 + th] = (bf16)v;
        xtail[(size_t)b * 256 + 128 + th] = (bf16)h0[(size_t)b * LH + th];
        __syncthreads();

        if (th < 64) {
            uint32_t off;
            if (th < 12) off = OFF_AB + (uint32_t)ids[h][th] * 256u;
            else if (th < 60) off = OFF_MV + (uint32_t)ids[h][th] * 256u;
            else if (th == 60) off = OFF_XT + (uint32_t)b * 512u;
            else if (th == 61) off = OFF_XT + (uint32_t)b * 512u + 256u;
            else off = OFF_XT;  // unused slots 62,63
            addrs[(size_t)b * 64 + th] = off;
        }
    } else if (bid < PREP_CW) {
        // ---- convert_w: cols [0,7680) direct; slot 60 = Wfold; then Whh ----
        bf16* Wcat = (bf16*)(ws + OFF_WCAT);
        float* nbias = (float*)(ws + OFF_NB);
        const int n = bid - PREP_BP;

        __shared__ float wrow[128];   // Wih[n][7680..7808)
        __shared__ float nbs[128];
        if (t < 128) wrow[t] = Wih[(size_t)n * KIH + 7680 + t];
        else nbs[t - 128] = numb[t - 128];
        __syncthreads();

        const float* src_ih = Wih + (size_t)n * KIH;
        bf16* dst = Wcat + (size_t)n * KTOT;
        for (int k4 = t; k4 < 1920; k4 += 256) {   // 7680/4
            const int k = k4 * 4;
            const float4 v = *(const float4*)(src_ih + k);
            bf16x4 o = {(bf16)v.x, (bf16)v.y, (bf16)v.z, (bf16)v.w};
            *(bf16x4*)(dst + k) = o;
        }
        if (t < 84) {
            // Wfold[n][t] = sum_e Wih[n][7680+e] * numW[e][t]
            float acc = 0.f;
#pragma unroll 4
            for (int e = 0; e < 128; ++e)
                acc += wrow[e] * numW[e * 84 + t];
            dst[7680 + t] = (bf16)acc;
        } else if (t < 128) {
            dst[7680 + t] = (bf16)0.f;     // padding cols (x is zero there too)
        } else {
            const int tt = t - 128;
            dst[KIH + tt] = (bf16)Whh[(size_t)n * LH + tt];
        }
        if (t == 255) {
            float a = 0.f;
#pragma unroll 4
            for (int e = 0; e < 128; ++e) a += wrow[e] * nbs[e];
            nbias[n] = a;
        }
    } else if (bid < PREP_CE) {
        // ---- convert_emb: 4 elems/thread, float4 -> bf16x4 ----
        bf16* ab8 = (bf16*)(ws + OFF_AB);
        bf16* mv8 = (bf16*)(ws + OFF_MV);
        const int i = ((bid - PREP_CW) * 256 + t) * 4;   // 0..153596
        const bool isab = i < 300 * 128;
        const float4 v = isab ? *(const float4*)(ab_emb + i)
                              : *(const float4*)(mv_emb + (i - 300 * 128));
        bf16x4 o = {(bf16)v.x, (bf16)v.y, (bf16)v.z, (bf16)v.w};
        if (isab) *(bf16x4*)(ab8 + i) = o;
        else *(bf16x4*)(mv8 + (i - 300 * 128)) = o;
    } else {
        // ---- pack MLP weight fragments (B-frag: lane n=l&15, k=(l>>4)*8+j) --
        bf16* W1f = (bf16*)(ws + OFF_W1F);
        bf16* W2f = (bf16*)(ws + OFF_W2F);
        bf16* Waf = (bf16*)(ws + OFF_WAF);
        for (int e = t; e < 8192; e += 256) {     // W1 (64x128), fid = nt*4+kt
            const int j = e & 7, ln = (e >> 3) & 63, fid = e >> 9;
            const int kt = fid & 3, nt = fid >> 2;
            const int n = nt * 16 + (ln & 15);
            const int k = kt * 32 + (ln >> 4) * 8 + j;
            W1f[e] = (bf16)W1[n * 128 + k];
        }
        for (int e = t; e < 8192; e += 256) {     // W2 (128x64), fid = nt*2+kt
            const int j = e & 7, ln = (e >> 3) & 63, fid = e >> 9;
            const int kt = fid & 1, nt = fid >> 1;
            const int n = nt * 16 + (ln & 15);
            const int k = kt * 32 + (ln >> 4) * 8 + j;
            W2f[e] = (bf16)W2[n * 64 + k];
        }
        for (int e = t; e < 2048; e += 256) {     // Wa (9x128 zero-padded)
            const int j = e & 7, ln = (e >> 3) & 63, kt = e >> 9;
            const int n = ln & 15;
            const int k = kt * 32 + (ln >> 4) * 8 + j;
            Waf[e] = (n < 9) ? (bf16)Wa[n * 128 + k] : (bf16)0.f;
        }
    }
}

// ---------------------------------------------------------------------------
// Kernel 2: gpart[bz] = x @ Wcat.T partial  (x gathered on the fly)
// r0 structure (128x128 tile, BK=64, 31 steps, conflict-free XOR swizzle,
// 2 buffers, wk-split, grid 32x4x4) with ONE change: the per-step
// __syncthreads() (which drains vmcnt to 0, exposing the just-issued
// stage's full load latency every step) is replaced by
//   stage(i+1) ; s_waitcnt vmcnt(8) ; s_barrier ; compute(i) ; s_barrier
// vmcnt(8) waits only for tile i (issued a FULL STEP earlier; 8 newer
// loads for tile i+1 stay in flight across the barrier). The trailing
// barrier protects the 2-buffer WAR (stage(i+2) overwrites compute(i)'s
// buffer). Final tile peeled with vmcnt(0). Count check: 8 async16 per
// wave per stage; 16 outstanding at the wait -> vmcnt(8) == tile i landed.
// ---------------------------------------------------------------------------
__global__ __launch_bounds__(256, 2) void gemm_gates(
    const uint8_t* __restrict__ wsbase,
    const bf16* __restrict__ Wcat,
    const uint32_t* __restrict__ addrs,
    bf16* __restrict__ gpart) {
    __shared__ bf16 As[2][128 * 64];    // 2 x 16 KB
    __shared__ bf16 Bs[2][128 * 64];    // 2 x 16 KB
    __shared__ uint32_t adr[17][128];   // 8.5 KB

    const int tid = threadIdx.x;
    const int w = tid >> 6;       // wave 0..3
    const int lane = tid & 63;
    const int bm = blockIdx.x;    // 0..31
    const int bn = blockIdx.y;    // 0..3
    const int bz = blockIdx.z;    // 0..3
    const int kt_beg = bz * 31;
    const int kt_end = kt_beg + 31;

    // preload this block's (row, slot) offsets
    const int s0 = kt_beg >> 1;
    const int ns = ((kt_end - 1) >> 1) - s0 + 1;   // <= 17
    for (int i = tid; i < ns * 128; i += 256) {
        adr[i >> 7][i & 127] =
            addrs[(size_t)(bm * 128 + (i & 127)) * 64 + s0 + (i >> 7)];
    }

    const int r_l = lane >> 3;                  // staging row within 8-row group
    const int sc16 = ((lane & 7) ^ r_l) * 16;   // XOR-swizzled 16B chunk (bytes)

    const int wn = w & 1;         // n-half: cols wn*64 .. wn*64+63
    const int wk = w >> 1;        // k-slice: elems wk*32 .. wk*32+31 of each BK
    const int n0 = wn * 64;
    const int kk8 = wk * 4 + (lane >> 4);       // global column chunk for frags
    const int fl = lane & 15;

    f32x4 acc[8][4];
#pragma unroll
    for (int i = 0; i < 8; ++i)
#pragma unroll
        for (int j = 0; j < 4; ++j)
#pragma unroll
            for (int r = 0; r < 4; ++r) acc[i][j][r] = 0.f;

    __syncthreads();  // adr visible

    auto stage = [&](int kt, int pb) {
        const int k0 = kt * 64;
        const int sl = (kt >> 1) - s0;
        const int hb = (kt & 1) * 128;
#pragma unroll
        for (int j = 0; j < 4; ++j) {
            const int row = (w * 4 + j) * 8 + r_l;
            const uint8_t* gsrc = wsbase + adr[sl][row] + hb + sc16;
            async16(gsrc, (void*)&As[pb][((w * 4 + j) * 64 + lane) * 8]);
        }
#pragma unroll
        for (int j = 0; j < 4; ++j) {
            const int row = (w * 4 + j) * 8 + r_l;
            const bf16* gsrc = Wcat + (size_t)(bn * 128 + row) * KTOT + k0 + (sc16 >> 1);
            async16(gsrc, (void*)&Bs[pb][((w * 4 + j) * 64 + lane) * 8]);
        }
    };

    auto compute = [&](int pb) {
        const bf16* Ab = &As[pb][0];
        const bf16* Bb = &Bs[pb][0];
        bf16x8 bfr[4];
#pragma unroll
        for (int tj = 0; tj < 4; ++tj) {
            const int n = n0 + tj * 16 + fl;
            bfr[tj] = *(const bf16x8*)&Bb[n * 64 + ((kk8 ^ (n & 7)) * 8)];
        }
#pragma unroll
        for (int ti = 0; ti < 8; ++ti) {
            const int m = ti * 16 + fl;
            const bf16x8 af = *(const bf16x8*)&Ab[m * 64 + ((kk8 ^ (m & 7)) * 8)];
#pragma unroll
            for (int tj = 0; tj < 4; ++tj)
                acc[ti][tj] = __builtin_amdgcn_mfma_f32_16x16x32_bf16(
                    af, bfr[tj], acc[ti][tj], 0, 0, 0);
        }
    };

    stage(kt_beg, 0);   // prologue: 8 loads in flight

    // main loop: tiles kt_beg .. kt_end-2, counted vmcnt(8)
    for (int kt = kt_beg; kt < kt_end - 1; ++kt) {
        const int pb = (kt - kt_beg) & 1;
        stage(kt + 1, pb ^ 1);                           // 16 in flight
        asm volatile("s_waitcnt vmcnt(8)" ::: "memory"); // tile kt landed (mine)
        __builtin_amdgcn_sched_barrier(0);
        __builtin_amdgcn_s_barrier();                    // all waves: kt landed
        __builtin_amdgcn_sched_barrier(0);
        compute(pb);
        __builtin_amdgcn_s_barrier();                    // done reading pb
    }
    // peeled final tile
    asm volatile("s_waitcnt vmcnt(0)" ::: "memory");
    __builtin_amdgcn_sched_barrier(0);
    __builtin_amdgcn_s_barrier();
    __builtin_amdgcn_sched_barrier(0);
    compute((kt_end - 1 - kt_beg) & 1);

    // ---- reduce wk-partials through LDS (As/Bs are dead now) ----
    __syncthreads();
    float* red = (wn == 0) ? (float*)&As[0][0] : (float*)&Bs[0][0];  // 32 KB each
    if (wk == 1) {
#pragma unroll
        for (int ti = 0; ti < 8; ++ti)
#pragma unroll
            for (int tj = 0; tj < 4; ++tj)
#pragma unroll
                for (int r = 0; r < 4; ++r)
                    red[((ti * 4 + tj) * 4 + r) * 64 + lane] = acc[ti][tj][r];
    }
    __syncthreads();

    if (wk == 0) {
        bf16* gdst = gpart + (size_t)bz * BATCH * NG;
        const int mlo = (lane >> 4) * 4;
#pragma unroll
        for (int ti = 0; ti < 8; ++ti)
#pragma unroll
            for (int tj = 0; tj < 4; ++tj) {
                const int mg = bm * 128 + ti * 16 + mlo;
                const int ng = bn * 128 + n0 + tj * 16 + fl;
                bf16* dst = gdst + (size_t)mg * NG + ng;
#pragma unroll
                for (int r = 0; r < 4; ++r)
                    dst[(size_t)r * NG] = (bf16)(
                        acc[ti][tj][r] + red[((ti * 4 + tj) * 4 + r) * 64 + lane]);
            }
    }
}

// ---------------------------------------------------------------------------
// Kernel 3: fused tail = split-K reduce + LSTM pointwise + MLP head.
// (verbatim from round-3 passing version)
// ---------------------------------------------------------------------------
__global__ __launch_bounds__(256) void tail(
    const bf16* __restrict__ gpart,
    const float* __restrict__ bih, const float* __restrict__ bhh,
    const float* __restrict__ nbias, const float* __restrict__ c0,
    const float* __restrict__ mask,
    const bf16* __restrict__ W1f, const bf16* __restrict__ W2f,
    const bf16* __restrict__ Waf,
    const float* __restrict__ b1, const float* __restrict__ b2,
    const float* __restrict__ ba,
    float* __restrict__ out) {
    __shared__ bf16 hS[16 * 128];    // 4 KB
    __shared__ bf16 uS[16 * 64];     // 2 KB
    __shared__ bf16 fS[16 * 128];    // 4 KB

    const int t = threadIdx.x;
    const int bid = blockIdx.x;
    const int b0 = bid * 16;

    // --- phase A: gate reduction + LSTM, 8 units/thread ---
    {
        const int r = t >> 4;               // row 0..15
        const int uc = (t & 15) * 8;        // unit chunk
        const int b = b0 + r;

        float gv[4][8];
#pragma unroll
        for (int q = 0; q < 4; ++q)
#pragma unroll
            for (int hh = 0; hh < 2; ++hh) {
                const f32x4 va = *(const f32x4*)(bih + q * 128 + uc + hh * 4);
                const f32x4 vb = *(const f32x4*)(bhh + q * 128 + uc + hh * 4);
                const f32x4 vn = *(const f32x4*)(nbias + q * 128 + uc + hh * 4);
#pragma unroll
                for (int j = 0; j < 4; ++j)
                    gv[q][hh * 4 + j] = va[j] + vb[j] + vn[j];
            }
#pragma unroll
        for (int z = 0; z < SPLITK; ++z) {
            const bf16* gz = gpart + ((size_t)z * BATCH + b) * NG;
#pragma unroll
            for (int q = 0; q < 4; ++q) {
                const bf16x8 v = *(const bf16x8*)(gz + q * 128 + uc);
#pragma unroll
                for (int j = 0; j < 8; ++j) gv[q][j] += (float)v[j];
            }
        }

        const f32x4 c0a = *(const f32x4*)(c0 + (size_t)b * LH + uc);
        const f32x4 c0b = *(const f32x4*)(c0 + (size_t)b * LH + uc + 4);
        float h1v[8], c1v[8];
        bf16x8 hv8;
#pragma unroll
        for (int j = 0; j < 8; ++j) {
            const float iv = 1.f / (1.f + __expf(-gv[0][j]));
            const float fv = 1.f / (1.f + __expf(-gv[1][j]));
            const float gg = tanhf(gv[2][j]);
            const float ov = 1.f / (1.f + __expf(-gv[3][j]));
            const float c0j = (j < 4) ? c0a[j] : c0b[j - 4];
            const float c1 = fv * c0j + iv * gg;
            const float h1 = ov * tanhf(c1);
            c1v[j] = c1;
            h1v[j] = h1;
            hv8[j] = (bf16)h1;
        }
        *(bf16x8*)&hS[r * 128 + uc] = hv8;
        *(f32x4*)(out + O_H1 + (size_t)b * LH + uc) = *(const f32x4*)&h1v[0];
        *(f32x4*)(out + O_H1 + (size_t)b * LH + uc + 4) = *(const f32x4*)&h1v[4];
        *(f32x4*)(out + O_C1 + (size_t)b * LH + uc) = *(const f32x4*)&c1v[0];
        *(f32x4*)(out + O_C1 + (size_t)b * LH + uc + 4) = *(const f32x4*)&c1v[4];
    }
    __syncthreads();

    // --- phase B: MLP head on wave 0 ---
    const int nl = t & 15, kg = (t & 63) >> 4;

    if (t < 64) {
        bf16x8 ah[4];
#pragma unroll
        for (int kt = 0; kt < 4; ++kt)
            ah[kt] = *(const bf16x8*)&hS[nl * 128 + kt * 32 + kg * 8];
#pragma unroll
        for (int nt = 0; nt < 4; ++nt) {
            f32x4 a = {0.f, 0.f, 0.f, 0.f};
#pragma unroll
            for (int kt = 0; kt < 4; ++kt)
                a = __builtin_amdgcn_mfma_f32_16x16x32_bf16(
                    ah[kt], *(const bf16x8*)&W1f[((nt * 4 + kt) * 64 + t) * 8],
                    a, 0, 0, 0);
            const int n = nt * 16 + nl;
            const float bb = b1[n];
#pragma unroll
            for (int rr = 0; rr < 4; ++rr)
                uS[(kg * 4 + rr) * 64 + n] = (bf16)fmaxf(a[rr] + bb, 0.f);
        }
    }
    __syncthreads();

    if (t < 64) {
        bf16x8 au[2];
#pragma unroll
        for (int kt = 0; kt < 2; ++kt)
            au[kt] = *(const bf16x8*)&uS[nl * 64 + kt * 32 + kg * 8];
#pragma unroll
        for (int nt = 0; nt < 8; ++nt) {
            f32x4 a = {0.f, 0.f, 0.f, 0.f};
#pragma unroll
            for (int kt = 0; kt < 2; ++kt)
                a = __builtin_amdgcn_mfma_f32_16x16x32_bf16(
                    au[kt], *(const bf16x8*)&W2f[((nt * 2 + kt) * 64 + t) * 8],
                    a, 0, 0, 0);
            const int n = nt * 16 + nl;
            const float bb = b2[n];
#pragma unroll
            for (int rr = 0; rr < 4; ++rr)
                fS[(kg * 4 + rr) * 128 + n] = (bf16)(a[rr] + bb);
        }
    }
    __syncthreads();

    if (t < 64) {
        bf16x8 afr[4];
#pragma unroll
        for (int kt = 0; kt < 4; ++kt)
            afr[kt] = *(const bf16x8*)&fS[nl * 128 + kt * 32 + kg * 8];

        f32x4 lg4 = {0.f, 0.f, 0.f, 0.f};
#pragma unroll
        for (int kt = 0; kt < 4; ++kt)
            lg4 = __builtin_amdgcn_mfma_f32_16x16x32_bf16(
                afr[kt], *(const bf16x8*)&Waf[(kt * 64 + t) * 8], lg4, 0, 0, 0);

        const float bav = (nl < 9) ? ba[nl] : 0.f;

#pragma unroll
        for (int rr = 0; rr < 4; ++rr) {
            const int b = b0 + kg * 4 + rr;
            float lg = (nl < 9) ? lg4[rr] + bav : -1e30f;
            float mx = lg;
#pragma unroll
            for (int off = 1; off < 16; off <<= 1)
                mx = fmaxf(mx, __shfl_xor(mx, off, 64));
            const float e = (nl < 9) ? __expf(lg - mx) : 0.f;
            const float mv = (nl < 9) ? mask[(size_t)b * 9 + nl] : 0.f;
            float tot = e, ms = e * mv;
#pragma unroll
            for (int off = 1; off < 16; off <<= 1) {
                tot += __shfl_xor(tot, off, 64);
                ms += __shfl_xor(ms, off, 64);
            }
            if (nl < 9)
                out[(size_t)b * 9 + nl] = (ms > 0.f) ? e * mv / ms : e / tot;
        }
    }
}

// ---------------------------------------------------------------------------
extern "C" void kernel_launch(void* const* d_in, const int* in_sizes, int n_in,
                              void* d_out, int out_size, void* d_ws, size_t ws_size,
                              hipStream_t stream) {
    const int* ab_ids = (const int*)d_in[0];
    const int* mv_ids = (const int*)d_in[1];
    const float* numerical = (const float*)d_in[2];
    const float* mask = (const float*)d_in[3];
    const float* h0 = (const float*)d_in[4];
    const float* c0 = (const float*)d_in[5];
    const float* ab_emb = (const float*)d_in[6];
    const float* mv_emb = (const float*)d_in[7];
    const float* numW = (const float*)d_in[8];
    const float* numb = (const float*)d_in[9];
    const float* Wih = (const float*)d_in[10];
    const float* Whh = (const float*)d_in[11];
    const float* bih = (const float*)d_in[12];
    const float* bhh = (const float*)d_in[13];
    const float* W1 = (const float*)d_in[14];
    const float* b1 = (const float*)d_in[15];
    const float* W2 = (const float*)d_in[16];
    const float* b2 = (const float*)d_in[17];
    const float* Wa = (const float*)d_in[18];
    const float* ba = (const float*)d_in[19];
    float* out = (float*)d_out;

    uint8_t* ws = (uint8_t*)d_ws;
    bf16* Wcat = (bf16*)(ws + OFF_WCAT);
    bf16* gpart = (bf16*)(ws + OFF_GPART);
    uint32_t* addrs = (uint32_t*)(ws + OFF_ADDR);
    bf16* W1f = (bf16*)(ws + OFF_W1F);
    bf16* W2f = (bf16*)(ws + OFF_W2F);
    bf16* Waf = (bf16*)(ws + OFF_WAF);
    float* nbias = (float*)(ws + OFF_NB);

    prep<<<PREP_TOT, 256, 0, stream>>>(
        ab_ids, mv_ids, numerical, h0, numW, numb, Wih, Whh, ab_emb, mv_emb,
        W1, W2, Wa, ws);
    gemm_gates<<<dim3(32, 4, SPLITK), 256, 0, stream>>>(ws, Wcat, addrs, gpart);
    tail<<<BATCH / 16, 256, 0, stream>>>(gpart, bih, bhh, nbias, c0, mask,
                                         W1f, W2f, Waf, b1, b2, ba, out);
}